// Round 11
// baseline (880.403 us; speedup 1.0000x reference)
//
#include <hip/hip_runtime.h>

#define HH 128

typedef __attribute__((ext_vector_type(8))) short bf16x8;
typedef __attribute__((ext_vector_type(4))) float f32x4;

__device__ __forceinline__ unsigned short f2bf(float f){
  unsigned int u = __builtin_bit_cast(unsigned int, f);
  u += 0x7FFFu + ((u >> 16) & 1u);        // round-to-nearest-even
  return (unsigned short)(u >> 16);
}
__device__ __forceinline__ float bf2f(unsigned int lo16){
  return __builtin_bit_cast(float, lo16 << 16);
}
__device__ __forceinline__ float silu_f(float x){
  return x / (1.f + __expf(-x));
}
__device__ __forceinline__ bf16x8 pack8(const float* p){
  float4 u0 = *(const float4*)(p);
  float4 u1 = *(const float4*)(p + 4);
  bf16x8 t;
  t[0]=(short)f2bf(u0.x); t[1]=(short)f2bf(u0.y); t[2]=(short)f2bf(u0.z); t[3]=(short)f2bf(u0.w);
  t[4]=(short)f2bf(u1.x); t[5]=(short)f2bf(u1.y); t[6]=(short)f2bf(u1.z); t[7]=(short)f2bf(u1.w);
  return t;
}

// ---------------- utility ----------------
__global__ void zero_kernel(int* __restrict__ p, int n){
  int i = blockIdx.x*256 + threadIdx.x;
  if (i < n) p[i] = 0;
}

__global__ void tobf_kernel(const float* __restrict__ in, unsigned short* __restrict__ out, int n4){
  int i = blockIdx.x*256 + threadIdx.x;
  if (i < n4){
    float4 v = *(const float4*)(in + (size_t)i*4);
    uint2 r;
    r.x = (unsigned int)f2bf(v.x) | ((unsigned int)f2bf(v.y) << 16);
    r.y = (unsigned int)f2bf(v.z) | ((unsigned int)f2bf(v.w) << 16);
    *(uint2*)(out + (size_t)i*4) = r;
  }
}

// W[k][c] (K x 128, f32) -> wT[c][k] (128 x K, bf16)
__global__ void wtr_kernel(const float* __restrict__ W, unsigned short* __restrict__ wT, int K){
  int idx = blockIdx.x*256 + threadIdx.x;
  if (idx < K*128){
    int k = idx >> 7, c = idx & 127;
    wT[c*K + k] = f2bf(W[idx]);
  }
}

// ---------------- CSR build ----------------
__global__ void hist_kernel(const int* __restrict__ row, int* __restrict__ deg, int E){
  int e = blockIdx.x*256 + threadIdx.x;
  if (e < E) atomicAdd(&deg[row[e]], 1);
}

__global__ void scan_kernel(const int* __restrict__ deg, int* __restrict__ rowstart,
                            int* __restrict__ cursor, int N){
  __shared__ int part[1024];
  int t = threadIdx.x;
  int chunk = (N + 1023) >> 10;
  int base = t * chunk;
  int s = 0;
  for (int j = 0; j < chunk; ++j){ int i = base + j; if (i < N) s += deg[i]; }
  part[t] = s;
  __syncthreads();
  for (int off = 1; off < 1024; off <<= 1){
    int v = (t >= off) ? part[t - off] : 0;
    __syncthreads();
    part[t] += v;
    __syncthreads();
  }
  int run = part[t] - s;   // exclusive prefix
  for (int j = 0; j < chunk; ++j){
    int i = base + j;
    if (i < N){ rowstart[i] = run; cursor[i] = run; run += deg[i]; }
  }
  if (t == 1023) rowstart[N] = part[1023];
}

__global__ void scatter_kernel(const int* __restrict__ row, int* __restrict__ cursor,
                               int* __restrict__ csr, int* __restrict__ destp, int E){
  int e = blockIdx.x*256 + threadIdx.x;
  if (e < E){
    int r = row[e];
    int p = atomicAdd(&cursor[r], 1);
    csr[p] = e;
    destp[p] = r;
  }
}

// ---------------- fused edge MLPs + aggregation (r10 + cross-tile gather prefetch) ----------------
// 768 threads = 12 waves; wave w owns edges [16w,16w+16) of a 192-edge tile.
// chunk = 12 atoms.  Weights staged in LDS once per pass.  LDS 148.5 KB -> 12 waves/CU.
// NEW: at tile t the full index+data chain for tile t+1 (csr -> colidx/destp ->
// atom/dist/dir) is issued right after a[] is captured, so each link hides
// under tile t's MFMA/LDS body.  Pass-1 aggregation reuses the prefetched
// eid/col/dest/dir registers (no reloads).
__global__ __launch_bounds__(768, 3) void fused_edge_kernel(
    const unsigned short* __restrict__ atom_bf,
    const unsigned short* __restrict__ force_bf,
    const float* __restrict__ dir,  const unsigned short* __restrict__ dist_bf,
    const int* __restrict__ colidx,
    const int* __restrict__ rowstart, const int* __restrict__ csr,
    const int* __restrict__ destp,
    const float* __restrict__ Wm1, const float* __restrict__ bm1,
    const float* __restrict__ Wm2, const float* __restrict__ bm2,
    const float* __restrict__ Wv1, const float* __restrict__ bv1,
    const float* __restrict__ Wv2, const float* __restrict__ bv2,
    float* __restrict__ scalar_agg, float* __restrict__ vec_agg,
    int N, int nchunks)
{
  __shared__ __align__(16) unsigned short sW1[128*168];    // 43008 B
  __shared__ __align__(16) unsigned short sW2[128*136];    // 34816 B
  __shared__ __align__(16) unsigned short hbuf[12*16*136]; // 52224 B
  __shared__ float accU[12*3*HH];                          // 18432 B (pass0 uses 12*HH)

  const int tid = threadIdx.x;
  const int w = tid >> 6, lane = tid & 63;
  const int l15 = lane & 15, lg = lane >> 4;
  unsigned short* hb = &hbuf[w*16*136];

  #pragma unroll 1
  for (int pass = 0; pass < 2; ++pass){
    const float* W1 = pass ? Wv1 : Wm1;
    const float* W2 = pass ? Wv2 : Wm2;
    const float* B1 = pass ? bv1 : bm1;
    const float* B2 = pass ? bv2 : bm2;
    __syncthreads();
    for (int idx = tid; idx < 160*128; idx += 768){
      int k = idx >> 7, c = idx & 127;
      sW1[c*168 + k] = f2bf(W1[idx]);
    }
    for (int idx = tid; idx < 128*128; idx += 768){
      int k = idx >> 7, c = idx & 127;
      sW2[c*136 + k] = f2bf(W2[idx]);
    }
    __syncthreads();
    float bb1[8], bb2[8];
    #pragma unroll
    for (int n = 0; n < 8; ++n){ bb1[n] = B1[n*16 + l15]; bb2[n] = B2[n*16 + l15]; }

    for (int chunk = blockIdx.x; chunk < nchunks; chunk += gridDim.x){
      const int i0 = chunk * 12;
      const int i1 = (i0 + 12 < N) ? (i0 + 12) : N;
      const int p0 = rowstart[i0];
      const int pend = rowstart[i1];
      {
        const int ztot = pass ? 12*3*HH : 12*HH;
        for (int idx = tid; idx < ztot; idx += 768) accU[idx] = 0.f;
      }
      __syncthreads();

      const int ntile = (pend - p0 + 191) / 192;

      // ---- prefetch tile 0 (index chain + data) ----
      int pa_n = p0 + (w << 4) + l15;
      if (pa_n >= pend) pa_n = pend - 1;
      int eid_n = csr[pa_n];
      int ca_n  = colidx[eid_n];
      int dst_n = destp[pa_n];
      float dx_n = 0.f, dy_n = 0.f, dz_n = 0.f;
      if (pass){
        dx_n = dir[(size_t)eid_n*3 + 0];
        dy_n = dir[(size_t)eid_n*3 + 1];
        dz_n = dir[(size_t)eid_n*3 + 2];
      }
      bf16x8 Ap[5];
      {
        const unsigned short* ar = atom_bf + (size_t)ca_n*HH + lg*8;
        #pragma unroll
        for (int kt = 0; kt < 4; ++kt) Ap[kt] = *(const bf16x8*)(ar + kt*32);
        Ap[4] = *(const bf16x8*)(dist_bf + (size_t)eid_n*32 + lg*8);
      }

      for (int t = 0; t < ntile; ++t){
        const int tb = p0 + t*192 + (w << 4);
        if (tb < pend){
          // ---- capture current tile's prefetched regs ----
          const int ca = ca_n, dstA = dst_n;
          const float dxA = dx_n, dyA = dy_n, dzA = dz_n;
          bf16x8 a[5];
          #pragma unroll
          for (int q = 0; q < 5; ++q) a[q] = Ap[q];

          // ---- issue prefetch for tile t+1 (hides under this tile's body) ----
          const int tb2 = tb + 192;
          if (tb2 < pend){
            int p2 = tb2 + l15;
            if (p2 >= pend) p2 = pend - 1;
            eid_n = csr[p2];
            ca_n  = colidx[eid_n];
            dst_n = destp[p2];
            if (pass){
              dx_n = dir[(size_t)eid_n*3 + 0];
              dy_n = dir[(size_t)eid_n*3 + 1];
              dz_n = dir[(size_t)eid_n*3 + 2];
            }
            const unsigned short* ar2 = atom_bf + (size_t)ca_n*HH + lg*8;
            #pragma unroll
            for (int kt = 0; kt < 4; ++kt) Ap[kt] = *(const bf16x8*)(ar2 + kt*32);
            Ap[4] = *(const bf16x8*)(dist_bf + (size_t)eid_n*32 + lg*8);
          }

          // ---- layer 1 ----
          f32x4 acc[8];
          #pragma unroll
          for (int n = 0; n < 8; ++n){ f32x4 tt = {bb1[n],bb1[n],bb1[n],bb1[n]}; acc[n] = tt; }
          #pragma unroll
          for (int kt = 0; kt < 5; ++kt){
            #pragma unroll
            for (int n = 0; n < 8; ++n){
              bf16x8 bf = *(const bf16x8*)&sW1[(n*16 + l15)*168 + kt*32 + lg*8];
              acc[n] = __builtin_amdgcn_mfma_f32_16x16x32_bf16(a[kt], bf, acc[n], 0, 0, 0);
            }
          }
          // ---- silu + transpose through per-wave LDS ----
          #pragma unroll
          for (int n = 0; n < 8; ++n)
            #pragma unroll
            for (int j = 0; j < 4; ++j)
              hb[((lg<<2) + j)*136 + n*16 + l15] = f2bf(silu_f(acc[n][j]));
          // ---- layer 2 ----
          f32x4 acc2[8];
          #pragma unroll
          for (int n = 0; n < 8; ++n){ f32x4 tt = {bb2[n],bb2[n],bb2[n],bb2[n]}; acc2[n] = tt; }
          #pragma unroll
          for (int kt = 0; kt < 4; ++kt){
            bf16x8 a2 = *(const bf16x8*)&hb[l15*136 + kt*32 + lg*8];
            #pragma unroll
            for (int n = 0; n < 8; ++n){
              bf16x8 bf = *(const bf16x8*)&sW2[(n*16 + l15)*136 + kt*32 + lg*8];
              acc2[n] = __builtin_amdgcn_mfma_f32_16x16x32_bf16(a2, bf, acc2[n], 0, 0, 0);
            }
          }

          if (pass == 0){
            // ---- scalar aggregation: per-lane register run-merge ----
            const int pr = tb + (lg << 2);
            int dj[4];
            #pragma unroll
            for (int j = 0; j < 4; ++j){
              int p = pr + j;
              dj[j] = (p < pend) ? (destp[p] - i0) : -1;
            }
            #pragma unroll
            for (int n = 0; n < 8; ++n){
              const int h = n*16 + l15;
              int drun = -1; float vrun = 0.f;
              #pragma unroll
              for (int j = 0; j < 4; ++j){
                if (dj[j] == drun){ vrun += acc2[n][j]; }
                else {
                  if (drun >= 0) atomicAdd(&accU[drun*HH + h], vrun);
                  drun = dj[j]; vrun = acc2[n][j];
                }
              }
              if (drun >= 0) atomicAdd(&accU[drun*HH + h], vrun);
            }
          } else {
            // ---- vec aggregation: stage vw; gather uses prefetched regs ----
            #pragma unroll
            for (int n = 0; n < 8; ++n)
              #pragma unroll
              for (int j = 0; j < 4; ++j)
                hb[((lg<<2) + j)*136 + n*16 + l15] = f2bf(acc2[n][j]);

            const int nvalid = pend - tb;            // >= 1
            const int dstS = dstA - i0;
            const int ch = lane << 1;

            int drun = -1;
            float v00=0.f,v01=0.f,v10=0.f,v11=0.f,v20=0.f,v21=0.f;
            #pragma unroll
            for (int r = 0; r < 16; ++r){
              const int c  = __shfl(ca, r);          // readlane -> SGPR
              const int di = __shfl(dstS, r);
              const float d0 = __shfl(dxA, r);
              const float d1 = __shfl(dyA, r);
              const float d2 = __shfl(dzA, r);
              const unsigned short* fb = force_bf + (size_t)c*3*HH + ch;
              const unsigned int f0 = *(const unsigned int*)(fb);
              const unsigned int f1 = *(const unsigned int*)(fb + HH);
              const unsigned int f2 = *(const unsigned int*)(fb + 2*HH);
              const unsigned int vw2 = *(const unsigned int*)&hb[r*136 + ch];
              const bool valid = (r < nvalid);
              const float vl = valid ? bf2f(vw2 & 0xffffu) : 0.f;
              const float vh = valid ? bf2f(vw2 >> 16) : 0.f;
              if (di != drun){                       // wave-uniform scalar branch
                if (drun >= 0){
                  atomicAdd(&accU[(drun*3 + 0)*HH + ch],     v00);
                  atomicAdd(&accU[(drun*3 + 0)*HH + ch + 1], v01);
                  atomicAdd(&accU[(drun*3 + 1)*HH + ch],     v10);
                  atomicAdd(&accU[(drun*3 + 1)*HH + ch + 1], v11);
                  atomicAdd(&accU[(drun*3 + 2)*HH + ch],     v20);
                  atomicAdd(&accU[(drun*3 + 2)*HH + ch + 1], v21);
                }
                drun = di;
                v00=0.f; v01=0.f; v10=0.f; v11=0.f; v20=0.f; v21=0.f;
              }
              v00 = fmaf(vl, d0 + bf2f(f0 & 0xffffu), v00);
              v01 = fmaf(vh, d0 + bf2f(f0 >> 16),     v01);
              v10 = fmaf(vl, d1 + bf2f(f1 & 0xffffu), v10);
              v11 = fmaf(vh, d1 + bf2f(f1 >> 16),     v11);
              v20 = fmaf(vl, d2 + bf2f(f2 & 0xffffu), v20);
              v21 = fmaf(vh, d2 + bf2f(f2 >> 16),     v21);
            }
            if (drun >= 0){
              atomicAdd(&accU[(drun*3 + 0)*HH + ch],     v00);
              atomicAdd(&accU[(drun*3 + 0)*HH + ch + 1], v01);
              atomicAdd(&accU[(drun*3 + 1)*HH + ch],     v10);
              atomicAdd(&accU[(drun*3 + 1)*HH + ch + 1], v11);
              atomicAdd(&accU[(drun*3 + 2)*HH + ch],     v20);
              atomicAdd(&accU[(drun*3 + 2)*HH + ch + 1], v21);
            }
          }
        }
      }
      __syncthreads();
      // ---- write chunk aggregates (exclusive ownership, plain stores) ----
      if (pass == 0){
        const int tot = (i1 - i0)*HH;
        for (int idx = tid; idx < tot; idx += 768)
          scalar_agg[(size_t)i0*HH + idx] = accU[idx];
      } else {
        const int tot = (i1 - i0)*3*HH;
        for (int idx = tid; idx < tot; idx += 768)
          vec_agg[(size_t)i0*3*HH + idx] = accU[idx];
      }
      __syncthreads();
    }
  }
}

// ---------------- node / force MLP: wave-specialized, reg-resident B (validated r7/r8) ----------------
template<bool IS_FORCE>
__global__ __launch_bounds__(512, 4) void node_mlp_kernel(
    const float* __restrict__ X0,   // atom_node (N,128)
    const float* __restrict__ X1,
    const float* __restrict__ FRC,  // force flat (N,3,128)
    const unsigned short* __restrict__ wT1, const float* __restrict__ b1,
    const unsigned short* __restrict__ wT2, const float* __restrict__ b2,
    float* __restrict__ out, int M)
{
  __shared__ __align__(16) unsigned short hbuf[16*136];

  const int tid = threadIdx.x;
  const int w = tid >> 6, lane = tid & 63;
  const int l15 = lane & 15, lg = lane >> 4;
  const int col = w*16 + l15;

  bf16x8 w1[8], w2[4];
  #pragma unroll
  for (int kt = 0; kt < 8; ++kt) w1[kt] = *(const bf16x8*)(wT1 + col*256 + kt*32 + lg*8);
  #pragma unroll
  for (int kt = 0; kt < 4; ++kt) w2[kt] = *(const bf16x8*)(wT2 + col*128 + kt*32 + lg*8);
  const float b1v = b1[col], b2v = b2[col];

  const int ntiles = (M + 15) >> 4;
  for (int tile = blockIdx.x; tile < ntiles; tile += gridDim.x){
    const int m0 = tile << 4;
    int r = m0 + l15;
    int rr = (r < M) ? r : (M - 1);

    bf16x8 a[8];
    {
      const float* x0 = X0 + (size_t)(IS_FORCE ? (rr/3) : rr) * HH + lg*8;
      #pragma unroll
      for (int kt = 0; kt < 4; ++kt) a[kt] = pack8(x0 + kt*32);
    }
    if (IS_FORCE){
      const float* x1 = X1 + (size_t)rr * HH + lg*8;
      #pragma unroll
      for (int kt = 0; kt < 4; ++kt) a[kt+4] = pack8(x1 + kt*32);
    } else {
      #pragma unroll
      for (int kt = 0; kt < 4; ++kt){
        const float* sp = X1  + (size_t)rr*HH   + kt*32 + lg*8;
        const float* fp = FRC + (size_t)rr*3*HH + kt*32 + lg*8;
        bf16x8 tv;
        #pragma unroll
        for (int q = 0; q < 8; ++q){
          float f0 = fp[q], f1 = fp[q + HH], f2 = fp[q + 2*HH];
          tv[q] = (short)f2bf(sp[q] + f0*f0 + f1*f1 + f2*f2);
        }
        a[kt+4] = tv;
      }
    }

    f32x4 acc = {b1v, b1v, b1v, b1v};
    #pragma unroll
    for (int kt = 0; kt < 8; ++kt)
      acc = __builtin_amdgcn_mfma_f32_16x16x32_bf16(a[kt], w1[kt], acc, 0, 0, 0);

    #pragma unroll
    for (int j = 0; j < 4; ++j)
      hbuf[((lg<<2) + j)*136 + col] = f2bf(silu_f(acc[j]));
    __syncthreads();

    f32x4 acc2 = {b2v, b2v, b2v, b2v};
    #pragma unroll
    for (int kt = 0; kt < 4; ++kt){
      bf16x8 a2 = *(const bf16x8*)&hbuf[l15*136 + kt*32 + lg*8];
      acc2 = __builtin_amdgcn_mfma_f32_16x16x32_bf16(a2, w2[kt], acc2, 0, 0, 0);
    }

    #pragma unroll
    for (int j = 0; j < 4; ++j){
      int R = m0 + (lg<<2) + j;
      if (R < M){
        size_t o = (size_t)R*HH + col;
        float y = acc2[j];
        float res;
        if (IS_FORCE){ float f = FRC[o]; res = f + y*f; }
        else         { res = X0[o] + y; }
        out[o] = res;
      }
    }
    __syncthreads();   // protect hbuf before next tile
  }
}

// ---------------- launch ----------------
extern "C" void kernel_launch(void* const* d_in, const int* in_sizes, int n_in,
                              void* d_out, int out_size, void* d_ws, size_t ws_size,
                              hipStream_t stream)
{
  const float* atom  = (const float*)d_in[0];
  const float* force = (const float*)d_in[1];
  const float* dir   = (const float*)d_in[2];
  const float* dist  = (const float*)d_in[3];
  const int*   eidx  = (const int*)d_in[4];
  const float* Wm1 = (const float*)d_in[5];  const float* bm1 = (const float*)d_in[6];
  const float* Wm2 = (const float*)d_in[7];  const float* bm2 = (const float*)d_in[8];
  const float* Wv1 = (const float*)d_in[9];  const float* bv1 = (const float*)d_in[10];
  const float* Wv2 = (const float*)d_in[11]; const float* bv2 = (const float*)d_in[12];
  const float* Wn1 = (const float*)d_in[13]; const float* bn1 = (const float*)d_in[14];
  const float* Wn2 = (const float*)d_in[15]; const float* bn2 = (const float*)d_in[16];
  const float* Wf1 = (const float*)d_in[17]; const float* bf1 = (const float*)d_in[18];
  const float* Wf2 = (const float*)d_in[19]; const float* bf2 = (const float*)d_in[20];

  const int N = in_sizes[0] / HH;
  const int E = in_sizes[2] / 3;
  const int* rowi = eidx;
  const int* coli = eidx + E;

  // workspace: CSR (~5.3 MB) + bf16 atom/force/dist (~61.5 MB) + bf16 wT (~0.25 MB)
  char* ws = (char*)d_ws;
  size_t off = 0;
  auto take = [&](size_t bytes) -> void* {
    void* p = (void*)(ws + off);
    off += (bytes + 255) & ~(size_t)255;
    return p;
  };
  int* deg      = (int*)take((size_t)(N+1)*4);
  int* rowstart = (int*)take((size_t)(N+1)*4);
  int* cursor   = (int*)take((size_t)N*4);
  int* csr      = (int*)take((size_t)E*4);
  int* destp    = (int*)take((size_t)E*4);
  unsigned short* atom_bf  = (unsigned short*)take((size_t)N*HH*2);
  unsigned short* force_bf = (unsigned short*)take((size_t)N*3*HH*2);
  unsigned short* dist_bf  = (unsigned short*)take((size_t)E*32*2);
  unsigned short* nT1 = (unsigned short*)take(256*128*2);
  unsigned short* nT2 = (unsigned short*)take(128*128*2);
  unsigned short* fT1 = (unsigned short*)take(256*128*2);
  unsigned short* fT2 = (unsigned short*)take(128*128*2);
  if (off > ws_size) return;  // degrade to wrong answer, not a page fault
  (void)n_in; (void)out_size;

  float* out0 = (float*)d_out;                    // scalar_agg -> atom_node_new
  float* out1 = out0 + (size_t)N*HH;              // vec_agg   -> force_node_new

  zero_kernel<<<(N+256)/256, 256, 0, stream>>>(deg, N+1);
  hist_kernel<<<(E+255)/256, 256, 0, stream>>>(rowi, deg, E);
  scan_kernel<<<1, 1024, 0, stream>>>(deg, rowstart, cursor, N);
  scatter_kernel<<<(E+255)/256, 256, 0, stream>>>(rowi, cursor, csr, destp, E);

  const int na4 = N*HH/4, nf4 = N*3*HH/4, nd4 = E*32/4;
  tobf_kernel<<<(na4+255)/256, 256, 0, stream>>>(atom,  atom_bf,  na4);
  tobf_kernel<<<(nf4+255)/256, 256, 0, stream>>>(force, force_bf, nf4);
  tobf_kernel<<<(nd4+255)/256, 256, 0, stream>>>(dist,  dist_bf,  nd4);

  wtr_kernel<<<(256*128+255)/256, 256, 0, stream>>>(Wn1, nT1, 256);
  wtr_kernel<<<(128*128+255)/256, 256, 0, stream>>>(Wn2, nT2, 128);
  wtr_kernel<<<(256*128+255)/256, 256, 0, stream>>>(Wf1, fT1, 256);
  wtr_kernel<<<(128*128+255)/256, 256, 0, stream>>>(Wf2, fT2, 128);

  const int nchunks = (N + 11) / 12;
  int fgrid = nchunks < 256 ? nchunks : 256;
  fused_edge_kernel<<<fgrid, 768, 0, stream>>>(atom_bf, force_bf, dir, dist_bf, coli,
      rowstart, csr, destp,
      Wm1,bm1, Wm2,bm2, Wv1,bv1, Wv2,bv2,
      out0, out1, N, nchunks);

  int nt_node  = (N + 15) >> 4;   if (nt_node  > 512) nt_node  = 512;
  int nt_force = (3*N + 15) >> 4; if (nt_force > 512) nt_force = 512;
  node_mlp_kernel<false><<<nt_node, 512, 0, stream>>>(atom, out0, force,
      nT1,bn1, nT2,bn2, out0, N);
  node_mlp_kernel<true><<<nt_force, 512, 0, stream>>>(atom, out1, force,
      fT1,bf1, fT2,bf2, out1, 3*N);
}

// Round 13
// 772.095 us; speedup vs baseline: 1.1403x; 1.1403x over previous
//
#include <hip/hip_runtime.h>

#define HH 128

typedef __attribute__((ext_vector_type(8))) short bf16x8;
typedef __attribute__((ext_vector_type(4))) float f32x4;

__device__ __forceinline__ unsigned short f2bf(float f){
  unsigned int u = __builtin_bit_cast(unsigned int, f);
  u += 0x7FFFu + ((u >> 16) & 1u);        // round-to-nearest-even
  return (unsigned short)(u >> 16);
}
__device__ __forceinline__ float bf2f(unsigned int lo16){
  return __builtin_bit_cast(float, lo16 << 16);
}
__device__ __forceinline__ float silu_f(float x){
  return x / (1.f + __expf(-x));
}
__device__ __forceinline__ bf16x8 pack8(const float* p){
  float4 u0 = *(const float4*)(p);
  float4 u1 = *(const float4*)(p + 4);
  bf16x8 t;
  t[0]=(short)f2bf(u0.x); t[1]=(short)f2bf(u0.y); t[2]=(short)f2bf(u0.z); t[3]=(short)f2bf(u0.w);
  t[4]=(short)f2bf(u1.x); t[5]=(short)f2bf(u1.y); t[6]=(short)f2bf(u1.z); t[7]=(short)f2bf(u1.w);
  return t;
}

// ---------------- utility ----------------
__global__ void zero_kernel(int* __restrict__ p, int n){
  int i = blockIdx.x*256 + threadIdx.x;
  if (i < n) p[i] = 0;
}

// fused f32 -> bf16 conversion for atom / force / dist (one launch)
__global__ void tobf3_kernel(const float* __restrict__ a, unsigned short* __restrict__ oa, int na4,
                             const float* __restrict__ f, unsigned short* __restrict__ of, int nf4,
                             const float* __restrict__ d, unsigned short* __restrict__ od, int nd4){
  int i = blockIdx.x*256 + threadIdx.x;
  const float* src; unsigned short* dst; int j;
  if (i < na4){ src = a; dst = oa; j = i; }
  else if (i < na4 + nf4){ src = f; dst = of; j = i - na4; }
  else if (i < na4 + nf4 + nd4){ src = d; dst = od; j = i - na4 - nf4; }
  else return;
  float4 v = *(const float4*)(src + (size_t)j*4);
  uint2 r;
  r.x = (unsigned int)f2bf(v.x) | ((unsigned int)f2bf(v.y) << 16);
  r.y = (unsigned int)f2bf(v.z) | ((unsigned int)f2bf(v.w) << 16);
  *(uint2*)(dst + (size_t)j*4) = r;
}

// fused W[k][c] -> wT[c][k] bf16 transpose for the 4 node/force weights (one launch)
__global__ void wtr4_kernel(const float* __restrict__ Wn1, unsigned short* __restrict__ nT1,
                            const float* __restrict__ Wn2, unsigned short* __restrict__ nT2,
                            const float* __restrict__ Wf1, unsigned short* __restrict__ fT1,
                            const float* __restrict__ Wf2, unsigned short* __restrict__ fT2){
  int i = blockIdx.x*256 + threadIdx.x;
  const float* W; unsigned short* T; int K, j;
  if (i < 256*128){ W = Wn1; T = nT1; K = 256; j = i; }
  else if (i < 256*128 + 128*128){ W = Wn2; T = nT2; K = 128; j = i - 256*128; }
  else if (i < 2*256*128 + 128*128){ W = Wf1; T = fT1; K = 256; j = i - 256*128 - 128*128; }
  else if (i < 2*256*128 + 2*128*128){ W = Wf2; T = fT2; K = 128; j = i - 2*256*128 - 128*128; }
  else return;
  int k = j >> 7, c = j & 127;
  T[c*K + k] = f2bf(W[j]);
}

// ---------------- CSR build ----------------
__global__ void hist_kernel(const int* __restrict__ row, int* __restrict__ deg, int E){
  int e = blockIdx.x*256 + threadIdx.x;
  if (e < E) atomicAdd(&deg[row[e]], 1);
}

__global__ void scan_kernel(const int* __restrict__ deg, int* __restrict__ rowstart,
                            int* __restrict__ cursor, int N){
  __shared__ int part[1024];
  int t = threadIdx.x;
  int chunk = (N + 1023) >> 10;
  int base = t * chunk;
  int s = 0;
  for (int j = 0; j < chunk; ++j){ int i = base + j; if (i < N) s += deg[i]; }
  part[t] = s;
  __syncthreads();
  for (int off = 1; off < 1024; off <<= 1){
    int v = (t >= off) ? part[t - off] : 0;
    __syncthreads();
    part[t] += v;
    __syncthreads();
  }
  int run = part[t] - s;   // exclusive prefix
  for (int j = 0; j < chunk; ++j){
    int i = base + j;
    if (i < N){ rowstart[i] = run; cursor[i] = run; run += deg[i]; }
  }
  if (t == 1023) rowstart[N] = part[1023];
}

__global__ void scatter_kernel(const int* __restrict__ row, int* __restrict__ cursor,
                               int* __restrict__ csr, int* __restrict__ destp, int E){
  int e = blockIdx.x*256 + threadIdx.x;
  if (e < E){
    int r = row[e];
    int p = atomicAdd(&cursor[r], 1);
    csr[p] = e;
    destp[p] = r;
  }
}

// ---------------- fused edge MLPs + aggregation (round-10 exact; nt dist load) ----------------
// 768 threads = 12 waves; wave w owns edges [16w,16w+16) of a 192-edge tile.
// chunk = 12 atoms.  Weights staged in LDS once per pass.  LDS 148.5 KB -> 12 waves/CU.
__global__ __launch_bounds__(768, 3) void fused_edge_kernel(
    const unsigned short* __restrict__ atom_bf,
    const unsigned short* __restrict__ force_bf,
    const float* __restrict__ dir,  const unsigned short* __restrict__ dist_bf,
    const int* __restrict__ colidx,
    const int* __restrict__ rowstart, const int* __restrict__ csr,
    const int* __restrict__ destp,
    const float* __restrict__ Wm1, const float* __restrict__ bm1,
    const float* __restrict__ Wm2, const float* __restrict__ bm2,
    const float* __restrict__ Wv1, const float* __restrict__ bv1,
    const float* __restrict__ Wv2, const float* __restrict__ bv2,
    float* __restrict__ scalar_agg, float* __restrict__ vec_agg,
    int N, int nchunks)
{
  __shared__ __align__(16) unsigned short sW1[128*168];    // 43008 B
  __shared__ __align__(16) unsigned short sW2[128*136];    // 34816 B
  __shared__ __align__(16) unsigned short hbuf[12*16*136]; // 52224 B
  __shared__ float accU[12*3*HH];                          // 18432 B (pass0 uses 12*HH)

  const int tid = threadIdx.x;
  const int w = tid >> 6, lane = tid & 63;
  const int l15 = lane & 15, lg = lane >> 4;
  unsigned short* hb = &hbuf[w*16*136];

  #pragma unroll 1
  for (int pass = 0; pass < 2; ++pass){
    const float* W1 = pass ? Wv1 : Wm1;
    const float* W2 = pass ? Wv2 : Wm2;
    const float* B1 = pass ? bv1 : bm1;
    const float* B2 = pass ? bv2 : bm2;
    __syncthreads();
    for (int idx = tid; idx < 160*128; idx += 768){
      int k = idx >> 7, c = idx & 127;
      sW1[c*168 + k] = f2bf(W1[idx]);
    }
    for (int idx = tid; idx < 128*128; idx += 768){
      int k = idx >> 7, c = idx & 127;
      sW2[c*136 + k] = f2bf(W2[idx]);
    }
    __syncthreads();
    float bb1[8], bb2[8];
    #pragma unroll
    for (int n = 0; n < 8; ++n){ bb1[n] = B1[n*16 + l15]; bb2[n] = B2[n*16 + l15]; }

    for (int chunk = blockIdx.x; chunk < nchunks; chunk += gridDim.x){
      const int i0 = chunk * 12;
      const int i1 = (i0 + 12 < N) ? (i0 + 12) : N;
      const int p0 = rowstart[i0];
      const int pend = rowstart[i1];
      {
        const int ztot = pass ? 12*3*HH : 12*HH;
        for (int idx = tid; idx < ztot; idx += 768) accU[idx] = 0.f;
      }
      __syncthreads();

      const int ntile = (pend - p0 + 191) / 192;
      for (int t = 0; t < ntile; ++t){
        const int tb = p0 + t*192 + (w << 4);
        if (tb < pend){
          // ---- A fragments (atom rows bf16 + dist bf16 nontemporal) ----
          int pa = tb + l15;
          if (pa >= pend) pa = pend - 1;
          const int eidA = csr[pa];
          const int ca = colidx[eidA];
          bf16x8 a[5];
          {
            const unsigned short* ar = atom_bf + (size_t)ca*HH + lg*8;
            #pragma unroll
            for (int kt = 0; kt < 4; ++kt) a[kt] = *(const bf16x8*)(ar + kt*32);
            a[4] = __builtin_nontemporal_load((const bf16x8*)(dist_bf + (size_t)eidA*32 + lg*8));
          }
          // ---- layer 1 ----
          f32x4 acc[8];
          #pragma unroll
          for (int n = 0; n < 8; ++n){ f32x4 tt = {bb1[n],bb1[n],bb1[n],bb1[n]}; acc[n] = tt; }
          #pragma unroll
          for (int kt = 0; kt < 5; ++kt){
            #pragma unroll
            for (int n = 0; n < 8; ++n){
              bf16x8 bf = *(const bf16x8*)&sW1[(n*16 + l15)*168 + kt*32 + lg*8];
              acc[n] = __builtin_amdgcn_mfma_f32_16x16x32_bf16(a[kt], bf, acc[n], 0, 0, 0);
            }
          }
          // ---- silu + transpose through per-wave LDS ----
          #pragma unroll
          for (int n = 0; n < 8; ++n)
            #pragma unroll
            for (int j = 0; j < 4; ++j)
              hb[((lg<<2) + j)*136 + n*16 + l15] = f2bf(silu_f(acc[n][j]));
          // ---- layer 2 ----
          f32x4 acc2[8];
          #pragma unroll
          for (int n = 0; n < 8; ++n){ f32x4 tt = {bb2[n],bb2[n],bb2[n],bb2[n]}; acc2[n] = tt; }
          #pragma unroll
          for (int kt = 0; kt < 4; ++kt){
            bf16x8 a2 = *(const bf16x8*)&hb[l15*136 + kt*32 + lg*8];
            #pragma unroll
            for (int n = 0; n < 8; ++n){
              bf16x8 bf = *(const bf16x8*)&sW2[(n*16 + l15)*136 + kt*32 + lg*8];
              acc2[n] = __builtin_amdgcn_mfma_f32_16x16x32_bf16(a2, bf, acc2[n], 0, 0, 0);
            }
          }

          if (pass == 0){
            // ---- scalar aggregation: per-lane register run-merge ----
            const int pr = tb + (lg << 2);
            int dj[4];
            #pragma unroll
            for (int j = 0; j < 4; ++j){
              int p = pr + j;
              dj[j] = (p < pend) ? (destp[p] - i0) : -1;
            }
            #pragma unroll
            for (int n = 0; n < 8; ++n){
              const int h = n*16 + l15;
              int drun = -1; float vrun = 0.f;
              #pragma unroll
              for (int j = 0; j < 4; ++j){
                if (dj[j] == drun){ vrun += acc2[n][j]; }
                else {
                  if (drun >= 0) atomicAdd(&accU[drun*HH + h], vrun);
                  drun = dj[j]; vrun = acc2[n][j];
                }
              }
              if (drun >= 0) atomicAdd(&accU[drun*HH + h], vrun);
            }
          } else {
            // ---- vec aggregation: stage vw, pipelined wave-uniform gather ----
            #pragma unroll
            for (int n = 0; n < 8; ++n)
              #pragma unroll
              for (int j = 0; j < 4; ++j)
                hb[((lg<<2) + j)*136 + n*16 + l15] = f2bf(acc2[n][j]);

            const int nvalid = pend - tb;            // >= 1
            int myp = tb + l15;
            if (myp >= pend) myp = pend - 1;
            const int eidS = csr[myp];
            const int dstS = destp[myp] - i0;
            const int colS = colidx[eidS];
            const float dxS = dir[(size_t)eidS*3 + 0];
            const float dyS = dir[(size_t)eidS*3 + 1];
            const float dzS = dir[(size_t)eidS*3 + 2];
            const int ch = lane << 1;

            int drun = -1;
            float v00=0.f,v01=0.f,v10=0.f,v11=0.f,v20=0.f,v21=0.f;
            #pragma unroll
            for (int r = 0; r < 16; ++r){
              const int c  = __shfl(colS, r);        // readlane -> SGPR
              const int di = __shfl(dstS, r);
              const float d0 = __shfl(dxS, r);
              const float d1 = __shfl(dyS, r);
              const float d2 = __shfl(dzS, r);
              const unsigned short* fb = force_bf + (size_t)c*3*HH + ch;
              const unsigned int f0 = *(const unsigned int*)(fb);
              const unsigned int f1 = *(const unsigned int*)(fb + HH);
              const unsigned int f2 = *(const unsigned int*)(fb + 2*HH);
              const unsigned int vw2 = *(const unsigned int*)&hb[r*136 + ch];
              const bool valid = (r < nvalid);
              const float vl = valid ? bf2f(vw2 & 0xffffu) : 0.f;
              const float vh = valid ? bf2f(vw2 >> 16) : 0.f;
              if (di != drun){                       // wave-uniform scalar branch
                if (drun >= 0){
                  atomicAdd(&accU[(drun*3 + 0)*HH + ch],     v00);
                  atomicAdd(&accU[(drun*3 + 0)*HH + ch + 1], v01);
                  atomicAdd(&accU[(drun*3 + 1)*HH + ch],     v10);
                  atomicAdd(&accU[(drun*3 + 1)*HH + ch + 1], v11);
                  atomicAdd(&accU[(drun*3 + 2)*HH + ch],     v20);
                  atomicAdd(&accU[(drun*3 + 2)*HH + ch + 1], v21);
                }
                drun = di;
                v00=0.f; v01=0.f; v10=0.f; v11=0.f; v20=0.f; v21=0.f;
              }
              v00 = fmaf(vl, d0 + bf2f(f0 & 0xffffu), v00);
              v01 = fmaf(vh, d0 + bf2f(f0 >> 16),     v01);
              v10 = fmaf(vl, d1 + bf2f(f1 & 0xffffu), v10);
              v11 = fmaf(vh, d1 + bf2f(f1 >> 16),     v11);
              v20 = fmaf(vl, d2 + bf2f(f2 & 0xffffu), v20);
              v21 = fmaf(vh, d2 + bf2f(f2 >> 16),     v21);
            }
            if (drun >= 0){
              atomicAdd(&accU[(drun*3 + 0)*HH + ch],     v00);
              atomicAdd(&accU[(drun*3 + 0)*HH + ch + 1], v01);
              atomicAdd(&accU[(drun*3 + 1)*HH + ch],     v10);
              atomicAdd(&accU[(drun*3 + 1)*HH + ch + 1], v11);
              atomicAdd(&accU[(drun*3 + 2)*HH + ch],     v20);
              atomicAdd(&accU[(drun*3 + 2)*HH + ch + 1], v21);
            }
          }
        }
      }
      __syncthreads();
      // ---- write chunk aggregates (exclusive ownership, plain stores) ----
      if (pass == 0){
        const int tot = (i1 - i0)*HH;
        for (int idx = tid; idx < tot; idx += 768)
          scalar_agg[(size_t)i0*HH + idx] = accU[idx];
      } else {
        const int tot = (i1 - i0)*3*HH;
        for (int idx = tid; idx < tot; idx += 768)
          vec_agg[(size_t)i0*3*HH + idx] = accU[idx];
      }
      __syncthreads();
    }
  }
}

// ---------------- node / force MLP: wave-specialized, reg-resident B (validated r7/r8) ----------------
template<bool IS_FORCE>
__global__ __launch_bounds__(512, 4) void node_mlp_kernel(
    const float* __restrict__ X0,   // atom_node (N,128)
    const float* __restrict__ X1,
    const float* __restrict__ FRC,  // force flat (N,3,128)
    const unsigned short* __restrict__ wT1, const float* __restrict__ b1,
    const unsigned short* __restrict__ wT2, const float* __restrict__ b2,
    float* __restrict__ out, int M)
{
  __shared__ __align__(16) unsigned short hbuf[16*136];

  const int tid = threadIdx.x;
  const int w = tid >> 6, lane = tid & 63;
  const int l15 = lane & 15, lg = lane >> 4;
  const int col = w*16 + l15;

  bf16x8 w1[8], w2[4];
  #pragma unroll
  for (int kt = 0; kt < 8; ++kt) w1[kt] = *(const bf16x8*)(wT1 + col*256 + kt*32 + lg*8);
  #pragma unroll
  for (int kt = 0; kt < 4; ++kt) w2[kt] = *(const bf16x8*)(wT2 + col*128 + kt*32 + lg*8);
  const float b1v = b1[col], b2v = b2[col];

  const int ntiles = (M + 15) >> 4;
  for (int tile = blockIdx.x; tile < ntiles; tile += gridDim.x){
    const int m0 = tile << 4;
    int r = m0 + l15;
    int rr = (r < M) ? r : (M - 1);

    bf16x8 a[8];
    {
      const float* x0 = X0 + (size_t)(IS_FORCE ? (rr/3) : rr) * HH + lg*8;
      #pragma unroll
      for (int kt = 0; kt < 4; ++kt) a[kt] = pack8(x0 + kt*32);
    }
    if (IS_FORCE){
      const float* x1 = X1 + (size_t)rr * HH + lg*8;
      #pragma unroll
      for (int kt = 0; kt < 4; ++kt) a[kt+4] = pack8(x1 + kt*32);
    } else {
      #pragma unroll
      for (int kt = 0; kt < 4; ++kt){
        const float* sp = X1  + (size_t)rr*HH   + kt*32 + lg*8;
        const float* fp = FRC + (size_t)rr*3*HH + kt*32 + lg*8;
        bf16x8 tv;
        #pragma unroll
        for (int q = 0; q < 8; ++q){
          float f0 = fp[q], f1 = fp[q + HH], f2 = fp[q + 2*HH];
          tv[q] = (short)f2bf(sp[q] + f0*f0 + f1*f1 + f2*f2);
        }
        a[kt+4] = tv;
      }
    }

    f32x4 acc = {b1v, b1v, b1v, b1v};
    #pragma unroll
    for (int kt = 0; kt < 8; ++kt)
      acc = __builtin_amdgcn_mfma_f32_16x16x32_bf16(a[kt], w1[kt], acc, 0, 0, 0);

    #pragma unroll
    for (int j = 0; j < 4; ++j)
      hbuf[((lg<<2) + j)*136 + col] = f2bf(silu_f(acc[j]));
    __syncthreads();

    f32x4 acc2 = {b2v, b2v, b2v, b2v};
    #pragma unroll
    for (int kt = 0; kt < 4; ++kt){
      bf16x8 a2 = *(const bf16x8*)&hbuf[l15*136 + kt*32 + lg*8];
      acc2 = __builtin_amdgcn_mfma_f32_16x16x32_bf16(a2, w2[kt], acc2, 0, 0, 0);
    }

    #pragma unroll
    for (int j = 0; j < 4; ++j){
      int R = m0 + (lg<<2) + j;
      if (R < M){
        size_t o = (size_t)R*HH + col;
        float y = acc2[j];
        float res;
        if (IS_FORCE){ float f = FRC[o]; res = f + y*f; }
        else         { res = X0[o] + y; }
        out[o] = res;
      }
    }
    __syncthreads();   // protect hbuf before next tile
  }
}

// ---------------- launch ----------------
extern "C" void kernel_launch(void* const* d_in, const int* in_sizes, int n_in,
                              void* d_out, int out_size, void* d_ws, size_t ws_size,
                              hipStream_t stream)
{
  const float* atom  = (const float*)d_in[0];
  const float* force = (const float*)d_in[1];
  const float* dir   = (const float*)d_in[2];
  const float* dist  = (const float*)d_in[3];
  const int*   eidx  = (const int*)d_in[4];
  const float* Wm1 = (const float*)d_in[5];  const float* bm1 = (const float*)d_in[6];
  const float* Wm2 = (const float*)d_in[7];  const float* bm2 = (const float*)d_in[8];
  const float* Wv1 = (const float*)d_in[9];  const float* bv1 = (const float*)d_in[10];
  const float* Wv2 = (const float*)d_in[11]; const float* bv2 = (const float*)d_in[12];
  const float* Wn1 = (const float*)d_in[13]; const float* bn1 = (const float*)d_in[14];
  const float* Wn2 = (const float*)d_in[15]; const float* bn2 = (const float*)d_in[16];
  const float* Wf1 = (const float*)d_in[17]; const float* bf1 = (const float*)d_in[18];
  const float* Wf2 = (const float*)d_in[19]; const float* bf2 = (const float*)d_in[20];

  const int N = in_sizes[0] / HH;
  const int E = in_sizes[2] / 3;
  const int* rowi = eidx;
  const int* coli = eidx + E;

  // workspace: CSR (~5.3 MB) + bf16 atom/force/dist (~61.5 MB) + bf16 wT (~0.25 MB)
  char* ws = (char*)d_ws;
  size_t off = 0;
  auto take = [&](size_t bytes) -> void* {
    void* p = (void*)(ws + off);
    off += (bytes + 255) & ~(size_t)255;
    return p;
  };
  int* deg      = (int*)take((size_t)(N+1)*4);
  int* rowstart = (int*)take((size_t)(N+1)*4);
  int* cursor   = (int*)take((size_t)N*4);
  int* csr      = (int*)take((size_t)E*4);
  int* destp    = (int*)take((size_t)E*4);
  unsigned short* atom_bf  = (unsigned short*)take((size_t)N*HH*2);
  unsigned short* force_bf = (unsigned short*)take((size_t)N*3*HH*2);
  unsigned short* dist_bf  = (unsigned short*)take((size_t)E*32*2);
  unsigned short* nT1 = (unsigned short*)take(256*128*2);
  unsigned short* nT2 = (unsigned short*)take(128*128*2);
  unsigned short* fT1 = (unsigned short*)take(256*128*2);
  unsigned short* fT2 = (unsigned short*)take(128*128*2);
  if (off > ws_size) return;  // degrade to wrong answer, not a page fault
  (void)n_in; (void)out_size;

  float* out0 = (float*)d_out;                    // scalar_agg -> atom_node_new
  float* out1 = out0 + (size_t)N*HH;              // vec_agg   -> force_node_new

  zero_kernel<<<(N+256)/256, 256, 0, stream>>>(deg, N+1);
  hist_kernel<<<(E+255)/256, 256, 0, stream>>>(rowi, deg, E);
  scan_kernel<<<1, 1024, 0, stream>>>(deg, rowstart, cursor, N);
  scatter_kernel<<<(E+255)/256, 256, 0, stream>>>(rowi, cursor, csr, destp, E);

  const int na4 = N*HH/4, nf4 = N*3*HH/4, nd4 = E*32/4;
  const int ncv = na4 + nf4 + nd4;
  tobf3_kernel<<<(ncv+255)/256, 256, 0, stream>>>(atom, atom_bf, na4,
                                                  force, force_bf, nf4,
                                                  dist, dist_bf, nd4);

  const int nwtr = 2*256*128 + 2*128*128;
  wtr4_kernel<<<(nwtr+255)/256, 256, 0, stream>>>(Wn1, nT1, Wn2, nT2, Wf1, fT1, Wf2, fT2);

  const int nchunks = (N + 11) / 12;
  int fgrid = nchunks < 256 ? nchunks : 256;
  fused_edge_kernel<<<fgrid, 768, 0, stream>>>(atom_bf, force_bf, dir, dist_bf, coli,
      rowstart, csr, destp,
      Wm1,bm1, Wm2,bm2, Wv1,bv1, Wv2,bv2,
      out0, out1, N, nchunks);

  int nt_node  = (N + 15) >> 4;   if (nt_node  > 512) nt_node  = 512;
  int nt_force = (3*N + 15) >> 4; if (nt_force > 512) nt_force = 512;
  node_mlp_kernel<false><<<nt_node, 512, 0, stream>>>(atom, out0, force,
      nT1,bn1, nT2,bn2, out0, N);
  node_mlp_kernel<true><<<nt_force, 512, 0, stream>>>(atom, out1, force,
      fT1,bf1, fT2,bf2, out1, 3*N);
}

// Round 14
// 734.627 us; speedup vs baseline: 1.1984x; 1.0510x over previous
//
#include <hip/hip_runtime.h>

#define HH 128

typedef __attribute__((ext_vector_type(8))) short bf16x8;
typedef __attribute__((ext_vector_type(4))) float f32x4;

__device__ __forceinline__ unsigned short f2bf(float f){
  unsigned int u = __builtin_bit_cast(unsigned int, f);
  u += 0x7FFFu + ((u >> 16) & 1u);        // round-to-nearest-even
  return (unsigned short)(u >> 16);
}
__device__ __forceinline__ float bf2f(unsigned int lo16){
  return __builtin_bit_cast(float, lo16 << 16);
}
__device__ __forceinline__ float silu_f(float x){
  return x / (1.f + __expf(-x));
}
__device__ __forceinline__ bf16x8 pack8(const float* p){
  float4 u0 = *(const float4*)(p);
  float4 u1 = *(const float4*)(p + 4);
  bf16x8 t;
  t[0]=(short)f2bf(u0.x); t[1]=(short)f2bf(u0.y); t[2]=(short)f2bf(u0.z); t[3]=(short)f2bf(u0.w);
  t[4]=(short)f2bf(u1.x); t[5]=(short)f2bf(u1.y); t[6]=(short)f2bf(u1.z); t[7]=(short)f2bf(u1.w);
  return t;
}

// ---------------- utility ----------------
__global__ void zero_kernel(int* __restrict__ p, int n){
  int i = blockIdx.x*256 + threadIdx.x;
  if (i < n) p[i] = 0;
}

// fused f32->bf16 conversion (atom/force/dist) + weight transposes (one launch)
__global__ void conv_kernel(const float* __restrict__ a, unsigned short* __restrict__ oa, int na4,
                            const float* __restrict__ f, unsigned short* __restrict__ of, int nf4,
                            const float* __restrict__ d, unsigned short* __restrict__ od, int nd4,
                            const float* __restrict__ Wn1, unsigned short* __restrict__ nT1,
                            const float* __restrict__ Wn2, unsigned short* __restrict__ nT2,
                            const float* __restrict__ Wf1, unsigned short* __restrict__ fT1,
                            const float* __restrict__ Wf2, unsigned short* __restrict__ fT2){
  int i = blockIdx.x*256 + threadIdx.x;
  const int ncv = na4 + nf4 + nd4;
  if (i < ncv){
    const float* src; unsigned short* dst; int j;
    if (i < na4){ src = a; dst = oa; j = i; }
    else if (i < na4 + nf4){ src = f; dst = of; j = i - na4; }
    else { src = d; dst = od; j = i - na4 - nf4; }
    float4 v = *(const float4*)(src + (size_t)j*4);
    uint2 r;
    r.x = (unsigned int)f2bf(v.x) | ((unsigned int)f2bf(v.y) << 16);
    r.y = (unsigned int)f2bf(v.z) | ((unsigned int)f2bf(v.w) << 16);
    *(uint2*)(dst + (size_t)j*4) = r;
    return;
  }
  int q = i - ncv;
  const float* W; unsigned short* T; int K, j;
  if (q < 256*128){ W = Wn1; T = nT1; K = 256; j = q; }
  else if (q < 256*128 + 128*128){ W = Wn2; T = nT2; K = 128; j = q - 256*128; }
  else if (q < 2*256*128 + 128*128){ W = Wf1; T = fT1; K = 256; j = q - 256*128 - 128*128; }
  else if (q < 2*256*128 + 2*128*128){ W = Wf2; T = fT2; K = 128; j = q - 2*256*128 - 128*128; }
  else return;
  int k = j >> 7, c = j & 127;
  T[c*K + k] = f2bf(W[j]);
}

// ---------------- CSR build ----------------
__global__ void hist_kernel(const int* __restrict__ row, int* __restrict__ deg, int E){
  int e = blockIdx.x*256 + threadIdx.x;
  if (e < E) atomicAdd(&deg[row[e]], 1);
}

__global__ void scan_kernel(const int* __restrict__ deg, int* __restrict__ rowstart,
                            int* __restrict__ cursor, int N){
  __shared__ int part[1024];
  int t = threadIdx.x;
  int chunk = (N + 1023) >> 10;
  int base = t * chunk;
  int s = 0;
  for (int j = 0; j < chunk; ++j){ int i = base + j; if (i < N) s += deg[i]; }
  part[t] = s;
  __syncthreads();
  for (int off = 1; off < 1024; off <<= 1){
    int v = (t >= off) ? part[t - off] : 0;
    __syncthreads();
    part[t] += v;
    __syncthreads();
  }
  int run = part[t] - s;   // exclusive prefix
  for (int j = 0; j < chunk; ++j){
    int i = base + j;
    if (i < N){ rowstart[i] = run; cursor[i] = run; run += deg[i]; }
  }
  if (t == 1023) rowstart[N] = part[1023];
}

__global__ void scatter_kernel(const int* __restrict__ row, int* __restrict__ cursor,
                               int* __restrict__ csr, int* __restrict__ destp, int E){
  int e = blockIdx.x*256 + threadIdx.x;
  if (e < E){
    int r = row[e];
    int p = atomicAdd(&cursor[r], 1);
    csr[p] = e;
    destp[p] = r;
  }
}

// ---------------- fused edge MLPs + aggregation (r13 body; chunk = 16 atoms) ----------------
// 768 threads = 12 waves; wave w owns edges [16w,16w+16) of a 192-edge tile.
// chunk = 16 atoms (~512 edges ~= 3 tiles, 2.8 sigma from the 4-tile boundary;
// vs chunk=12 whose mean sat EXACTLY on the 2-tile boundary -> 2.49 tiles avg).
// Weights staged in LDS once per pass.  LDS 154.6 KB -> 1 block/CU, 12 waves.
__global__ __launch_bounds__(768, 3) void fused_edge_kernel(
    const unsigned short* __restrict__ atom_bf,
    const unsigned short* __restrict__ force_bf,
    const float* __restrict__ dir,  const unsigned short* __restrict__ dist_bf,
    const int* __restrict__ colidx,
    const int* __restrict__ rowstart, const int* __restrict__ csr,
    const int* __restrict__ destp,
    const float* __restrict__ Wm1, const float* __restrict__ bm1,
    const float* __restrict__ Wm2, const float* __restrict__ bm2,
    const float* __restrict__ Wv1, const float* __restrict__ bv1,
    const float* __restrict__ Wv2, const float* __restrict__ bv2,
    float* __restrict__ scalar_agg, float* __restrict__ vec_agg,
    int N, int nchunks)
{
  __shared__ __align__(16) unsigned short sW1[128*168];    // 43008 B
  __shared__ __align__(16) unsigned short sW2[128*136];    // 34816 B
  __shared__ __align__(16) unsigned short hbuf[12*16*136]; // 52224 B
  __shared__ float accU[16*3*HH];                          // 24576 B (pass0 uses 16*HH)

  const int tid = threadIdx.x;
  const int w = tid >> 6, lane = tid & 63;
  const int l15 = lane & 15, lg = lane >> 4;
  unsigned short* hb = &hbuf[w*16*136];

  #pragma unroll 1
  for (int pass = 0; pass < 2; ++pass){
    const float* W1 = pass ? Wv1 : Wm1;
    const float* W2 = pass ? Wv2 : Wm2;
    const float* B1 = pass ? bv1 : bm1;
    const float* B2 = pass ? bv2 : bm2;
    __syncthreads();
    for (int idx = tid; idx < 160*128; idx += 768){
      int k = idx >> 7, c = idx & 127;
      sW1[c*168 + k] = f2bf(W1[idx]);
    }
    for (int idx = tid; idx < 128*128; idx += 768){
      int k = idx >> 7, c = idx & 127;
      sW2[c*136 + k] = f2bf(W2[idx]);
    }
    __syncthreads();
    float bb1[8], bb2[8];
    #pragma unroll
    for (int n = 0; n < 8; ++n){ bb1[n] = B1[n*16 + l15]; bb2[n] = B2[n*16 + l15]; }

    for (int chunk = blockIdx.x; chunk < nchunks; chunk += gridDim.x){
      const int i0 = chunk << 4;
      const int i1 = (i0 + 16 < N) ? (i0 + 16) : N;
      const int p0 = rowstart[i0];
      const int pend = rowstart[i1];
      {
        const int ztot = pass ? 16*3*HH : 16*HH;
        for (int idx = tid; idx < ztot; idx += 768) accU[idx] = 0.f;
      }
      __syncthreads();

      const int ntile = (pend - p0 + 191) / 192;
      for (int t = 0; t < ntile; ++t){
        const int tb = p0 + t*192 + (w << 4);
        if (tb < pend){
          // ---- A fragments (atom rows bf16 + dist bf16 nontemporal) ----
          int pa = tb + l15;
          if (pa >= pend) pa = pend - 1;
          const int eidA = csr[pa];
          const int ca = colidx[eidA];
          bf16x8 a[5];
          {
            const unsigned short* ar = atom_bf + (size_t)ca*HH + lg*8;
            #pragma unroll
            for (int kt = 0; kt < 4; ++kt) a[kt] = *(const bf16x8*)(ar + kt*32);
            a[4] = __builtin_nontemporal_load((const bf16x8*)(dist_bf + (size_t)eidA*32 + lg*8));
          }
          // ---- layer 1 ----
          f32x4 acc[8];
          #pragma unroll
          for (int n = 0; n < 8; ++n){ f32x4 tt = {bb1[n],bb1[n],bb1[n],bb1[n]}; acc[n] = tt; }
          #pragma unroll
          for (int kt = 0; kt < 5; ++kt){
            #pragma unroll
            for (int n = 0; n < 8; ++n){
              bf16x8 bf = *(const bf16x8*)&sW1[(n*16 + l15)*168 + kt*32 + lg*8];
              acc[n] = __builtin_amdgcn_mfma_f32_16x16x32_bf16(a[kt], bf, acc[n], 0, 0, 0);
            }
          }
          // ---- silu + transpose through per-wave LDS ----
          #pragma unroll
          for (int n = 0; n < 8; ++n)
            #pragma unroll
            for (int j = 0; j < 4; ++j)
              hb[((lg<<2) + j)*136 + n*16 + l15] = f2bf(silu_f(acc[n][j]));
          // ---- layer 2 ----
          f32x4 acc2[8];
          #pragma unroll
          for (int n = 0; n < 8; ++n){ f32x4 tt = {bb2[n],bb2[n],bb2[n],bb2[n]}; acc2[n] = tt; }
          #pragma unroll
          for (int kt = 0; kt < 4; ++kt){
            bf16x8 a2 = *(const bf16x8*)&hb[l15*136 + kt*32 + lg*8];
            #pragma unroll
            for (int n = 0; n < 8; ++n){
              bf16x8 bf = *(const bf16x8*)&sW2[(n*16 + l15)*136 + kt*32 + lg*8];
              acc2[n] = __builtin_amdgcn_mfma_f32_16x16x32_bf16(a2, bf, acc2[n], 0, 0, 0);
            }
          }

          if (pass == 0){
            // ---- scalar aggregation: per-lane register run-merge ----
            const int pr = tb + (lg << 2);
            int dj[4];
            #pragma unroll
            for (int j = 0; j < 4; ++j){
              int p = pr + j;
              dj[j] = (p < pend) ? (destp[p] - i0) : -1;
            }
            #pragma unroll
            for (int n = 0; n < 8; ++n){
              const int h = n*16 + l15;
              int drun = -1; float vrun = 0.f;
              #pragma unroll
              for (int j = 0; j < 4; ++j){
                if (dj[j] == drun){ vrun += acc2[n][j]; }
                else {
                  if (drun >= 0) atomicAdd(&accU[drun*HH + h], vrun);
                  drun = dj[j]; vrun = acc2[n][j];
                }
              }
              if (drun >= 0) atomicAdd(&accU[drun*HH + h], vrun);
            }
          } else {
            // ---- vec aggregation: stage vw, pipelined wave-uniform gather ----
            #pragma unroll
            for (int n = 0; n < 8; ++n)
              #pragma unroll
              for (int j = 0; j < 4; ++j)
                hb[((lg<<2) + j)*136 + n*16 + l15] = f2bf(acc2[n][j]);

            const int nvalid = pend - tb;            // >= 1
            int myp = tb + l15;
            if (myp >= pend) myp = pend - 1;
            const int eidS = csr[myp];
            const int dstS = destp[myp] - i0;
            const int colS = colidx[eidS];
            const float dxS = dir[(size_t)eidS*3 + 0];
            const float dyS = dir[(size_t)eidS*3 + 1];
            const float dzS = dir[(size_t)eidS*3 + 2];
            const int ch = lane << 1;

            int drun = -1;
            float v00=0.f,v01=0.f,v10=0.f,v11=0.f,v20=0.f,v21=0.f;
            #pragma unroll
            for (int r = 0; r < 16; ++r){
              const int c  = __shfl(colS, r);        // readlane -> SGPR
              const int di = __shfl(dstS, r);
              const float d0 = __shfl(dxS, r);
              const float d1 = __shfl(dyS, r);
              const float d2 = __shfl(dzS, r);
              const unsigned short* fb = force_bf + (size_t)c*3*HH + ch;
              const unsigned int f0 = *(const unsigned int*)(fb);
              const unsigned int f1 = *(const unsigned int*)(fb + HH);
              const unsigned int f2 = *(const unsigned int*)(fb + 2*HH);
              const unsigned int vw2 = *(const unsigned int*)&hb[r*136 + ch];
              const bool valid = (r < nvalid);
              const float vl = valid ? bf2f(vw2 & 0xffffu) : 0.f;
              const float vh = valid ? bf2f(vw2 >> 16) : 0.f;
              if (di != drun){                       // wave-uniform scalar branch
                if (drun >= 0){
                  atomicAdd(&accU[(drun*3 + 0)*HH + ch],     v00);
                  atomicAdd(&accU[(drun*3 + 0)*HH + ch + 1], v01);
                  atomicAdd(&accU[(drun*3 + 1)*HH + ch],     v10);
                  atomicAdd(&accU[(drun*3 + 1)*HH + ch + 1], v11);
                  atomicAdd(&accU[(drun*3 + 2)*HH + ch],     v20);
                  atomicAdd(&accU[(drun*3 + 2)*HH + ch + 1], v21);
                }
                drun = di;
                v00=0.f; v01=0.f; v10=0.f; v11=0.f; v20=0.f; v21=0.f;
              }
              v00 = fmaf(vl, d0 + bf2f(f0 & 0xffffu), v00);
              v01 = fmaf(vh, d0 + bf2f(f0 >> 16),     v01);
              v10 = fmaf(vl, d1 + bf2f(f1 & 0xffffu), v10);
              v11 = fmaf(vh, d1 + bf2f(f1 >> 16),     v11);
              v20 = fmaf(vl, d2 + bf2f(f2 & 0xffffu), v20);
              v21 = fmaf(vh, d2 + bf2f(f2 >> 16),     v21);
            }
            if (drun >= 0){
              atomicAdd(&accU[(drun*3 + 0)*HH + ch],     v00);
              atomicAdd(&accU[(drun*3 + 0)*HH + ch + 1], v01);
              atomicAdd(&accU[(drun*3 + 1)*HH + ch],     v10);
              atomicAdd(&accU[(drun*3 + 1)*HH + ch + 1], v11);
              atomicAdd(&accU[(drun*3 + 2)*HH + ch],     v20);
              atomicAdd(&accU[(drun*3 + 2)*HH + ch + 1], v21);
            }
          }
        }
      }
      __syncthreads();
      // ---- write chunk aggregates (exclusive ownership, plain stores) ----
      if (pass == 0){
        const int tot = (i1 - i0)*HH;
        for (int idx = tid; idx < tot; idx += 768)
          scalar_agg[(size_t)i0*HH + idx] = accU[idx];
      } else {
        const int tot = (i1 - i0)*3*HH;
        for (int idx = tid; idx < tot; idx += 768)
          vec_agg[(size_t)i0*3*HH + idx] = accU[idx];
      }
      __syncthreads();
    }
  }
}

// ---------------- node + force MLPs fused in one launch (grid-partitioned) ----------------
template<bool IS_FORCE>
__device__ __forceinline__ void node_body(
    int bid, int grid,
    const float* __restrict__ X0, const float* __restrict__ X1,
    const float* __restrict__ FRC,
    const unsigned short* __restrict__ wT1, const float* __restrict__ b1,
    const unsigned short* __restrict__ wT2, const float* __restrict__ b2,
    float* __restrict__ out, int M, unsigned short* hbuf)
{
  const int tid = threadIdx.x;
  const int w = tid >> 6, lane = tid & 63;
  const int l15 = lane & 15, lg = lane >> 4;
  const int col = w*16 + l15;

  bf16x8 w1[8], w2[4];
  #pragma unroll
  for (int kt = 0; kt < 8; ++kt) w1[kt] = *(const bf16x8*)(wT1 + col*256 + kt*32 + lg*8);
  #pragma unroll
  for (int kt = 0; kt < 4; ++kt) w2[kt] = *(const bf16x8*)(wT2 + col*128 + kt*32 + lg*8);
  const float b1v = b1[col], b2v = b2[col];

  const int ntiles = (M + 15) >> 4;
  for (int tile = bid; tile < ntiles; tile += grid){
    const int m0 = tile << 4;
    int r = m0 + l15;
    int rr = (r < M) ? r : (M - 1);

    bf16x8 a[8];
    {
      const float* x0 = X0 + (size_t)(IS_FORCE ? (rr/3) : rr) * HH + lg*8;
      #pragma unroll
      for (int kt = 0; kt < 4; ++kt) a[kt] = pack8(x0 + kt*32);
    }
    if (IS_FORCE){
      const float* x1 = X1 + (size_t)rr * HH + lg*8;
      #pragma unroll
      for (int kt = 0; kt < 4; ++kt) a[kt+4] = pack8(x1 + kt*32);
    } else {
      #pragma unroll
      for (int kt = 0; kt < 4; ++kt){
        const float* sp = X1  + (size_t)rr*HH   + kt*32 + lg*8;
        const float* fp = FRC + (size_t)rr*3*HH + kt*32 + lg*8;
        bf16x8 tv;
        #pragma unroll
        for (int q = 0; q < 8; ++q){
          float f0 = fp[q], f1 = fp[q + HH], f2 = fp[q + 2*HH];
          tv[q] = (short)f2bf(sp[q] + f0*f0 + f1*f1 + f2*f2);
        }
        a[kt+4] = tv;
      }
    }

    f32x4 acc = {b1v, b1v, b1v, b1v};
    #pragma unroll
    for (int kt = 0; kt < 8; ++kt)
      acc = __builtin_amdgcn_mfma_f32_16x16x32_bf16(a[kt], w1[kt], acc, 0, 0, 0);

    #pragma unroll
    for (int j = 0; j < 4; ++j)
      hbuf[((lg<<2) + j)*136 + col] = f2bf(silu_f(acc[j]));
    __syncthreads();

    f32x4 acc2 = {b2v, b2v, b2v, b2v};
    #pragma unroll
    for (int kt = 0; kt < 4; ++kt){
      bf16x8 a2 = *(const bf16x8*)&hbuf[l15*136 + kt*32 + lg*8];
      acc2 = __builtin_amdgcn_mfma_f32_16x16x32_bf16(a2, w2[kt], acc2, 0, 0, 0);
    }

    #pragma unroll
    for (int j = 0; j < 4; ++j){
      int R = m0 + (lg<<2) + j;
      if (R < M){
        size_t o = (size_t)R*HH + col;
        float y = acc2[j];
        float res;
        if (IS_FORCE){ float f = FRC[o]; res = f + y*f; }
        else         { res = X0[o] + y; }
        out[o] = res;
      }
    }
    __syncthreads();   // protect hbuf before next tile
  }
}

__global__ __launch_bounds__(512, 4) void node_both_kernel(
    const float* __restrict__ atom, float* __restrict__ out0,
    float* __restrict__ out1, const float* __restrict__ force,
    const unsigned short* __restrict__ nT1, const float* __restrict__ bn1,
    const unsigned short* __restrict__ nT2, const float* __restrict__ bn2,
    const unsigned short* __restrict__ fT1, const float* __restrict__ bf1,
    const unsigned short* __restrict__ fT2, const float* __restrict__ bf2,
    int N, int gA, int gB)
{
  __shared__ __align__(16) unsigned short hbuf[16*136];
  if ((int)blockIdx.x < gA){
    node_body<false>(blockIdx.x, gA, atom, out0, force,
                     nT1, bn1, nT2, bn2, out0, N, hbuf);
  } else {
    node_body<true>(blockIdx.x - gA, gB, atom, out1, force,
                    fT1, bf1, fT2, bf2, out1, 3*N, hbuf);
  }
}

// ---------------- launch ----------------
extern "C" void kernel_launch(void* const* d_in, const int* in_sizes, int n_in,
                              void* d_out, int out_size, void* d_ws, size_t ws_size,
                              hipStream_t stream)
{
  const float* atom  = (const float*)d_in[0];
  const float* force = (const float*)d_in[1];
  const float* dir   = (const float*)d_in[2];
  const float* dist  = (const float*)d_in[3];
  const int*   eidx  = (const int*)d_in[4];
  const float* Wm1 = (const float*)d_in[5];  const float* bm1 = (const float*)d_in[6];
  const float* Wm2 = (const float*)d_in[7];  const float* bm2 = (const float*)d_in[8];
  const float* Wv1 = (const float*)d_in[9];  const float* bv1 = (const float*)d_in[10];
  const float* Wv2 = (const float*)d_in[11]; const float* bv2 = (const float*)d_in[12];
  const float* Wn1 = (const float*)d_in[13]; const float* bn1 = (const float*)d_in[14];
  const float* Wn2 = (const float*)d_in[15]; const float* bn2 = (const float*)d_in[16];
  const float* Wf1 = (const float*)d_in[17]; const float* bf1 = (const float*)d_in[18];
  const float* Wf2 = (const float*)d_in[19]; const float* bf2 = (const float*)d_in[20];

  const int N = in_sizes[0] / HH;
  const int E = in_sizes[2] / 3;
  const int* rowi = eidx;
  const int* coli = eidx + E;

  // workspace: CSR (~5.3 MB) + bf16 atom/force/dist (~61.5 MB) + bf16 wT (~0.25 MB)
  char* ws = (char*)d_ws;
  size_t off = 0;
  auto take = [&](size_t bytes) -> void* {
    void* p = (void*)(ws + off);
    off += (bytes + 255) & ~(size_t)255;
    return p;
  };
  int* deg      = (int*)take((size_t)(N+1)*4);
  int* rowstart = (int*)take((size_t)(N+1)*4);
  int* cursor   = (int*)take((size_t)N*4);
  int* csr      = (int*)take((size_t)E*4);
  int* destp    = (int*)take((size_t)E*4);
  unsigned short* atom_bf  = (unsigned short*)take((size_t)N*HH*2);
  unsigned short* force_bf = (unsigned short*)take((size_t)N*3*HH*2);
  unsigned short* dist_bf  = (unsigned short*)take((size_t)E*32*2);
  unsigned short* nT1 = (unsigned short*)take(256*128*2);
  unsigned short* nT2 = (unsigned short*)take(128*128*2);
  unsigned short* fT1 = (unsigned short*)take(256*128*2);
  unsigned short* fT2 = (unsigned short*)take(128*128*2);
  if (off > ws_size) return;  // degrade to wrong answer, not a page fault
  (void)n_in; (void)out_size;

  float* out0 = (float*)d_out;                    // scalar_agg -> atom_node_new
  float* out1 = out0 + (size_t)N*HH;              // vec_agg   -> force_node_new

  zero_kernel<<<(N+256)/256, 256, 0, stream>>>(deg, N+1);
  hist_kernel<<<(E+255)/256, 256, 0, stream>>>(rowi, deg, E);
  scan_kernel<<<1, 1024, 0, stream>>>(deg, rowstart, cursor, N);
  scatter_kernel<<<(E+255)/256, 256, 0, stream>>>(rowi, cursor, csr, destp, E);

  const int na4 = N*HH/4, nf4 = N*3*HH/4, nd4 = E*32/4;
  const int ntot = na4 + nf4 + nd4 + 2*256*128 + 2*128*128;
  conv_kernel<<<(ntot+255)/256, 256, 0, stream>>>(atom, atom_bf, na4,
                                                  force, force_bf, nf4,
                                                  dist, dist_bf, nd4,
                                                  Wn1, nT1, Wn2, nT2,
                                                  Wf1, fT1, Wf2, fT2);

  const int nchunks = (N + 15) >> 4;
  int fgrid = nchunks < 256 ? nchunks : 256;
  fused_edge_kernel<<<fgrid, 768, 0, stream>>>(atom_bf, force_bf, dir, dist_bf, coli,
      rowstart, csr, destp,
      Wm1,bm1, Wm2,bm2, Wv1,bv1, Wv2,bv2,
      out0, out1, N, nchunks);

  int gA = (N + 15) >> 4;   if (gA > 512) gA = 512;
  int gB = (3*N + 15) >> 4; if (gB > 512) gB = 512;
  node_both_kernel<<<gA + gB, 512, 0, stream>>>(atom, out0, out1, force,
      nT1, bn1, nT2, bn2, fT1, bf1, fT2, bf2, N, gA, gB);
}

// Round 15
// 706.558 us; speedup vs baseline: 1.2460x; 1.0397x over previous
//
#include <hip/hip_runtime.h>

#define HH 128

typedef __attribute__((ext_vector_type(8))) short bf16x8;
typedef __attribute__((ext_vector_type(4))) float f32x4;

__device__ __forceinline__ unsigned short f2bf(float f){
  unsigned int u = __builtin_bit_cast(unsigned int, f);
  u += 0x7FFFu + ((u >> 16) & 1u);        // round-to-nearest-even
  return (unsigned short)(u >> 16);
}
__device__ __forceinline__ float bf2f(unsigned int lo16){
  return __builtin_bit_cast(float, lo16 << 16);
}
__device__ __forceinline__ float silu_f(float x){
  return x / (1.f + __expf(-x));
}
__device__ __forceinline__ bf16x8 pack8(const float* p){
  float4 u0 = *(const float4*)(p);
  float4 u1 = *(const float4*)(p + 4);
  bf16x8 t;
  t[0]=(short)f2bf(u0.x); t[1]=(short)f2bf(u0.y); t[2]=(short)f2bf(u0.z); t[3]=(short)f2bf(u0.w);
  t[4]=(short)f2bf(u1.x); t[5]=(short)f2bf(u1.y); t[6]=(short)f2bf(u1.z); t[7]=(short)f2bf(u1.w);
  return t;
}

// ---------------- utility ----------------
__global__ void zero_kernel(int* __restrict__ p, int n){
  int i = blockIdx.x*256 + threadIdx.x;
  if (i < n) p[i] = 0;
}

// histogram + (f32->bf16 conversions and weight transposes) in one launch:
// threads [0,E) do the histogram atomic; threads [E, E+ncv+nwtr) do conversions.
__global__ void hist_conv_kernel(const int* __restrict__ row, int* __restrict__ deg, int E,
                                 const float* __restrict__ a, unsigned short* __restrict__ oa, int na4,
                                 const float* __restrict__ f, unsigned short* __restrict__ of, int nf4,
                                 const float* __restrict__ d, unsigned short* __restrict__ od, int nd4,
                                 const float* __restrict__ Wn1, unsigned short* __restrict__ nT1,
                                 const float* __restrict__ Wn2, unsigned short* __restrict__ nT2,
                                 const float* __restrict__ Wf1, unsigned short* __restrict__ fT1,
                                 const float* __restrict__ Wf2, unsigned short* __restrict__ fT2){
  int i = blockIdx.x*256 + threadIdx.x;
  if (i < E){ atomicAdd(&deg[row[i]], 1); return; }
  int ii = i - E;
  const int ncv = na4 + nf4 + nd4;
  if (ii < ncv){
    const float* src; unsigned short* dst; int j;
    if (ii < na4){ src = a; dst = oa; j = ii; }
    else if (ii < na4 + nf4){ src = f; dst = of; j = ii - na4; }
    else { src = d; dst = od; j = ii - na4 - nf4; }
    float4 v = *(const float4*)(src + (size_t)j*4);
    uint2 r;
    r.x = (unsigned int)f2bf(v.x) | ((unsigned int)f2bf(v.y) << 16);
    r.y = (unsigned int)f2bf(v.z) | ((unsigned int)f2bf(v.w) << 16);
    *(uint2*)(dst + (size_t)j*4) = r;
    return;
  }
  int q = ii - ncv;
  const float* W; unsigned short* T; int K, j;
  if (q < 256*128){ W = Wn1; T = nT1; K = 256; j = q; }
  else if (q < 256*128 + 128*128){ W = Wn2; T = nT2; K = 128; j = q - 256*128; }
  else if (q < 2*256*128 + 128*128){ W = Wf1; T = fT1; K = 256; j = q - 256*128 - 128*128; }
  else if (q < 2*256*128 + 2*128*128){ W = Wf2; T = fT2; K = 128; j = q - 2*256*128 - 128*128; }
  else return;
  int k = j >> 7, c = j & 127;
  T[c*K + k] = f2bf(W[j]);
}

// ---------------- CSR build ----------------
__global__ void scan_kernel(const int* __restrict__ deg, int* __restrict__ rowstart,
                            int* __restrict__ cursor, int N){
  __shared__ int part[1024];
  int t = threadIdx.x;
  int chunk = (N + 1023) >> 10;
  int base = t * chunk;
  int s = 0;
  for (int j = 0; j < chunk; ++j){ int i = base + j; if (i < N) s += deg[i]; }
  part[t] = s;
  __syncthreads();
  for (int off = 1; off < 1024; off <<= 1){
    int v = (t >= off) ? part[t - off] : 0;
    __syncthreads();
    part[t] += v;
    __syncthreads();
  }
  int run = part[t] - s;   // exclusive prefix
  for (int j = 0; j < chunk; ++j){
    int i = base + j;
    if (i < N){ rowstart[i] = run; cursor[i] = run; run += deg[i]; }
  }
  if (t == 1023) rowstart[N] = part[1023];
}

__global__ void scatter_kernel(const int* __restrict__ row, int* __restrict__ cursor,
                               int* __restrict__ csr, int* __restrict__ destp, int E){
  int e = blockIdx.x*256 + threadIdx.x;
  if (e < E){
    int r = row[e];
    int p = atomicAdd(&cursor[r], 1);
    csr[p] = e;
    destp[p] = r;
  }
}

// ---------------- fused edge MLPs + aggregation (r14 body, UNCHANGED) ----------------
// 768 threads = 12 waves; wave w owns edges [16w,16w+16) of a 192-edge tile.
// chunk = 16 atoms (~512 edges ~= 3 tiles).  Weights staged in LDS once per pass.
// LDS 154.6 KB -> 1 block/CU, 12 waves.
__global__ __launch_bounds__(768, 3) void fused_edge_kernel(
    const unsigned short* __restrict__ atom_bf,
    const unsigned short* __restrict__ force_bf,
    const float* __restrict__ dir,  const unsigned short* __restrict__ dist_bf,
    const int* __restrict__ colidx,
    const int* __restrict__ rowstart, const int* __restrict__ csr,
    const int* __restrict__ destp,
    const float* __restrict__ Wm1, const float* __restrict__ bm1,
    const float* __restrict__ Wm2, const float* __restrict__ bm2,
    const float* __restrict__ Wv1, const float* __restrict__ bv1,
    const float* __restrict__ Wv2, const float* __restrict__ bv2,
    float* __restrict__ scalar_agg, float* __restrict__ vec_agg,
    int N, int nchunks)
{
  __shared__ __align__(16) unsigned short sW1[128*168];    // 43008 B
  __shared__ __align__(16) unsigned short sW2[128*136];    // 34816 B
  __shared__ __align__(16) unsigned short hbuf[12*16*136]; // 52224 B
  __shared__ float accU[16*3*HH];                          // 24576 B (pass0 uses 16*HH)

  const int tid = threadIdx.x;
  const int w = tid >> 6, lane = tid & 63;
  const int l15 = lane & 15, lg = lane >> 4;
  unsigned short* hb = &hbuf[w*16*136];

  #pragma unroll 1
  for (int pass = 0; pass < 2; ++pass){
    const float* W1 = pass ? Wv1 : Wm1;
    const float* W2 = pass ? Wv2 : Wm2;
    const float* B1 = pass ? bv1 : bm1;
    const float* B2 = pass ? bv2 : bm2;
    __syncthreads();
    for (int idx = tid; idx < 160*128; idx += 768){
      int k = idx >> 7, c = idx & 127;
      sW1[c*168 + k] = f2bf(W1[idx]);
    }
    for (int idx = tid; idx < 128*128; idx += 768){
      int k = idx >> 7, c = idx & 127;
      sW2[c*136 + k] = f2bf(W2[idx]);
    }
    __syncthreads();
    float bb1[8], bb2[8];
    #pragma unroll
    for (int n = 0; n < 8; ++n){ bb1[n] = B1[n*16 + l15]; bb2[n] = B2[n*16 + l15]; }

    for (int chunk = blockIdx.x; chunk < nchunks; chunk += gridDim.x){
      const int i0 = chunk << 4;
      const int i1 = (i0 + 16 < N) ? (i0 + 16) : N;
      const int p0 = rowstart[i0];
      const int pend = rowstart[i1];
      {
        const int ztot = pass ? 16*3*HH : 16*HH;
        for (int idx = tid; idx < ztot; idx += 768) accU[idx] = 0.f;
      }
      __syncthreads();

      const int ntile = (pend - p0 + 191) / 192;
      for (int t = 0; t < ntile; ++t){
        const int tb = p0 + t*192 + (w << 4);
        if (tb < pend){
          // ---- A fragments (atom rows bf16 + dist bf16 nontemporal) ----
          int pa = tb + l15;
          if (pa >= pend) pa = pend - 1;
          const int eidA = csr[pa];
          const int ca = colidx[eidA];
          bf16x8 a[5];
          {
            const unsigned short* ar = atom_bf + (size_t)ca*HH + lg*8;
            #pragma unroll
            for (int kt = 0; kt < 4; ++kt) a[kt] = *(const bf16x8*)(ar + kt*32);
            a[4] = __builtin_nontemporal_load((const bf16x8*)(dist_bf + (size_t)eidA*32 + lg*8));
          }
          // ---- layer 1 ----
          f32x4 acc[8];
          #pragma unroll
          for (int n = 0; n < 8; ++n){ f32x4 tt = {bb1[n],bb1[n],bb1[n],bb1[n]}; acc[n] = tt; }
          #pragma unroll
          for (int kt = 0; kt < 5; ++kt){
            #pragma unroll
            for (int n = 0; n < 8; ++n){
              bf16x8 bf = *(const bf16x8*)&sW1[(n*16 + l15)*168 + kt*32 + lg*8];
              acc[n] = __builtin_amdgcn_mfma_f32_16x16x32_bf16(a[kt], bf, acc[n], 0, 0, 0);
            }
          }
          // ---- silu + transpose through per-wave LDS ----
          #pragma unroll
          for (int n = 0; n < 8; ++n)
            #pragma unroll
            for (int j = 0; j < 4; ++j)
              hb[((lg<<2) + j)*136 + n*16 + l15] = f2bf(silu_f(acc[n][j]));
          // ---- layer 2 ----
          f32x4 acc2[8];
          #pragma unroll
          for (int n = 0; n < 8; ++n){ f32x4 tt = {bb2[n],bb2[n],bb2[n],bb2[n]}; acc2[n] = tt; }
          #pragma unroll
          for (int kt = 0; kt < 4; ++kt){
            bf16x8 a2 = *(const bf16x8*)&hb[l15*136 + kt*32 + lg*8];
            #pragma unroll
            for (int n = 0; n < 8; ++n){
              bf16x8 bf = *(const bf16x8*)&sW2[(n*16 + l15)*136 + kt*32 + lg*8];
              acc2[n] = __builtin_amdgcn_mfma_f32_16x16x32_bf16(a2, bf, acc2[n], 0, 0, 0);
            }
          }

          if (pass == 0){
            // ---- scalar aggregation: per-lane register run-merge ----
            const int pr = tb + (lg << 2);
            int dj[4];
            #pragma unroll
            for (int j = 0; j < 4; ++j){
              int p = pr + j;
              dj[j] = (p < pend) ? (destp[p] - i0) : -1;
            }
            #pragma unroll
            for (int n = 0; n < 8; ++n){
              const int h = n*16 + l15;
              int drun = -1; float vrun = 0.f;
              #pragma unroll
              for (int j = 0; j < 4; ++j){
                if (dj[j] == drun){ vrun += acc2[n][j]; }
                else {
                  if (drun >= 0) atomicAdd(&accU[drun*HH + h], vrun);
                  drun = dj[j]; vrun = acc2[n][j];
                }
              }
              if (drun >= 0) atomicAdd(&accU[drun*HH + h], vrun);
            }
          } else {
            // ---- vec aggregation: stage vw, pipelined wave-uniform gather ----
            #pragma unroll
            for (int n = 0; n < 8; ++n)
              #pragma unroll
              for (int j = 0; j < 4; ++j)
                hb[((lg<<2) + j)*136 + n*16 + l15] = f2bf(acc2[n][j]);

            const int nvalid = pend - tb;            // >= 1
            int myp = tb + l15;
            if (myp >= pend) myp = pend - 1;
            const int eidS = csr[myp];
            const int dstS = destp[myp] - i0;
            const int colS = colidx[eidS];
            const float dxS = dir[(size_t)eidS*3 + 0];
            const float dyS = dir[(size_t)eidS*3 + 1];
            const float dzS = dir[(size_t)eidS*3 + 2];
            const int ch = lane << 1;

            int drun = -1;
            float v00=0.f,v01=0.f,v10=0.f,v11=0.f,v20=0.f,v21=0.f;
            #pragma unroll
            for (int r = 0; r < 16; ++r){
              const int c  = __shfl(colS, r);        // readlane -> SGPR
              const int di = __shfl(dstS, r);
              const float d0 = __shfl(dxS, r);
              const float d1 = __shfl(dyS, r);
              const float d2 = __shfl(dzS, r);
              const unsigned short* fb = force_bf + (size_t)c*3*HH + ch;
              const unsigned int f0 = *(const unsigned int*)(fb);
              const unsigned int f1 = *(const unsigned int*)(fb + HH);
              const unsigned int f2 = *(const unsigned int*)(fb + 2*HH);
              const unsigned int vw2 = *(const unsigned int*)&hb[r*136 + ch];
              const bool valid = (r < nvalid);
              const float vl = valid ? bf2f(vw2 & 0xffffu) : 0.f;
              const float vh = valid ? bf2f(vw2 >> 16) : 0.f;
              if (di != drun){                       // wave-uniform scalar branch
                if (drun >= 0){
                  atomicAdd(&accU[(drun*3 + 0)*HH + ch],     v00);
                  atomicAdd(&accU[(drun*3 + 0)*HH + ch + 1], v01);
                  atomicAdd(&accU[(drun*3 + 1)*HH + ch],     v10);
                  atomicAdd(&accU[(drun*3 + 1)*HH + ch + 1], v11);
                  atomicAdd(&accU[(drun*3 + 2)*HH + ch],     v20);
                  atomicAdd(&accU[(drun*3 + 2)*HH + ch + 1], v21);
                }
                drun = di;
                v00=0.f; v01=0.f; v10=0.f; v11=0.f; v20=0.f; v21=0.f;
              }
              v00 = fmaf(vl, d0 + bf2f(f0 & 0xffffu), v00);
              v01 = fmaf(vh, d0 + bf2f(f0 >> 16),     v01);
              v10 = fmaf(vl, d1 + bf2f(f1 & 0xffffu), v10);
              v11 = fmaf(vh, d1 + bf2f(f1 >> 16),     v11);
              v20 = fmaf(vl, d2 + bf2f(f2 & 0xffffu), v20);
              v21 = fmaf(vh, d2 + bf2f(f2 >> 16),     v21);
            }
            if (drun >= 0){
              atomicAdd(&accU[(drun*3 + 0)*HH + ch],     v00);
              atomicAdd(&accU[(drun*3 + 0)*HH + ch + 1], v01);
              atomicAdd(&accU[(drun*3 + 1)*HH + ch],     v10);
              atomicAdd(&accU[(drun*3 + 1)*HH + ch + 1], v11);
              atomicAdd(&accU[(drun*3 + 2)*HH + ch],     v20);
              atomicAdd(&accU[(drun*3 + 2)*HH + ch + 1], v21);
            }
          }
        }
      }
      __syncthreads();
      // ---- write chunk aggregates (exclusive ownership, plain stores) ----
      if (pass == 0){
        const int tot = (i1 - i0)*HH;
        for (int idx = tid; idx < tot; idx += 768)
          scalar_agg[(size_t)i0*HH + idx] = accU[idx];
      } else {
        const int tot = (i1 - i0)*3*HH;
        for (int idx = tid; idx < tot; idx += 768)
          vec_agg[(size_t)i0*3*HH + idx] = accU[idx];
      }
      __syncthreads();
    }
  }
}

// ---------------- node + force MLPs fused in one launch (grid-partitioned) ----------------
// A-fragments read from bf16 mirrors (atom_bf / force_bf); residual & epilogue
// read the original f32 arrays (precision of the output path unchanged).
template<bool IS_FORCE>
__device__ __forceinline__ void node_body(
    int bid, int grid,
    const unsigned short* __restrict__ X0b,  // atom_bf
    const float* __restrict__ X0f,           // atom f32 (residual)
    const float* __restrict__ X1,            // scalar_agg (out0) or vec_agg (out1), f32
    const float* __restrict__ FRC,           // force f32 (epilogue)
    const unsigned short* __restrict__ FRCb, // force_bf (vec_invariant squares)
    const unsigned short* __restrict__ wT1, const float* __restrict__ b1,
    const unsigned short* __restrict__ wT2, const float* __restrict__ b2,
    float* __restrict__ out, int M, unsigned short* hbuf)
{
  const int tid = threadIdx.x;
  const int w = tid >> 6, lane = tid & 63;
  const int l15 = lane & 15, lg = lane >> 4;
  const int col = w*16 + l15;

  bf16x8 w1[8], w2[4];
  #pragma unroll
  for (int kt = 0; kt < 8; ++kt) w1[kt] = *(const bf16x8*)(wT1 + col*256 + kt*32 + lg*8);
  #pragma unroll
  for (int kt = 0; kt < 4; ++kt) w2[kt] = *(const bf16x8*)(wT2 + col*128 + kt*32 + lg*8);
  const float b1v = b1[col], b2v = b2[col];

  const int ntiles = (M + 15) >> 4;
  for (int tile = bid; tile < ntiles; tile += grid){
    const int m0 = tile << 4;
    int r = m0 + l15;
    int rr = (r < M) ? r : (M - 1);

    bf16x8 a[8];
    {
      const unsigned short* x0 = X0b + (size_t)(IS_FORCE ? (rr/3) : rr) * HH + lg*8;
      #pragma unroll
      for (int kt = 0; kt < 4; ++kt) a[kt] = *(const bf16x8*)(x0 + kt*32);
    }
    if (IS_FORCE){
      const float* x1 = X1 + (size_t)rr * HH + lg*8;
      #pragma unroll
      for (int kt = 0; kt < 4; ++kt) a[kt+4] = pack8(x1 + kt*32);
    } else {
      #pragma unroll
      for (int kt = 0; kt < 4; ++kt){
        const float* sp = X1 + (size_t)rr*HH + kt*32 + lg*8;
        const unsigned short* fp = FRCb + (size_t)rr*3*HH + kt*32 + lg*8;
        bf16x8 tv;
        #pragma unroll
        for (int q = 0; q < 8; ++q){
          float f0 = bf2f(fp[q]), f1 = bf2f(fp[q + HH]), f2 = bf2f(fp[q + 2*HH]);
          tv[q] = (short)f2bf(sp[q] + f0*f0 + f1*f1 + f2*f2);
        }
        a[kt+4] = tv;
      }
    }

    f32x4 acc = {b1v, b1v, b1v, b1v};
    #pragma unroll
    for (int kt = 0; kt < 8; ++kt)
      acc = __builtin_amdgcn_mfma_f32_16x16x32_bf16(a[kt], w1[kt], acc, 0, 0, 0);

    #pragma unroll
    for (int j = 0; j < 4; ++j)
      hbuf[((lg<<2) + j)*136 + col] = f2bf(silu_f(acc[j]));
    __syncthreads();

    f32x4 acc2 = {b2v, b2v, b2v, b2v};
    #pragma unroll
    for (int kt = 0; kt < 4; ++kt){
      bf16x8 a2 = *(const bf16x8*)&hbuf[l15*136 + kt*32 + lg*8];
      acc2 = __builtin_amdgcn_mfma_f32_16x16x32_bf16(a2, w2[kt], acc2, 0, 0, 0);
    }

    #pragma unroll
    for (int j = 0; j < 4; ++j){
      int R = m0 + (lg<<2) + j;
      if (R < M){
        size_t o = (size_t)R*HH + col;
        float y = acc2[j];
        float res;
        if (IS_FORCE){ float f = FRC[o]; res = f + y*f; }
        else         { res = X0f[o] + y; }
        out[o] = res;
      }
    }
    __syncthreads();   // protect hbuf before next tile
  }
}

__global__ __launch_bounds__(512, 4) void node_both_kernel(
    const unsigned short* __restrict__ atom_bf, const float* __restrict__ atom,
    const unsigned short* __restrict__ force_bf,
    float* __restrict__ out0, float* __restrict__ out1,
    const float* __restrict__ force,
    const unsigned short* __restrict__ nT1, const float* __restrict__ bn1,
    const unsigned short* __restrict__ nT2, const float* __restrict__ bn2,
    const unsigned short* __restrict__ fT1, const float* __restrict__ bf1,
    const unsigned short* __restrict__ fT2, const float* __restrict__ bf2,
    int N, int gA, int gB)
{
  __shared__ __align__(16) unsigned short hbuf[16*136];
  if ((int)blockIdx.x < gA){
    node_body<false>(blockIdx.x, gA, atom_bf, atom, out0, force, force_bf,
                     nT1, bn1, nT2, bn2, out0, N, hbuf);
  } else {
    node_body<true>(blockIdx.x - gA, gB, atom_bf, atom, out1, force, force_bf,
                    fT1, bf1, fT2, bf2, out1, 3*N, hbuf);
  }
}

// ---------------- launch ----------------
extern "C" void kernel_launch(void* const* d_in, const int* in_sizes, int n_in,
                              void* d_out, int out_size, void* d_ws, size_t ws_size,
                              hipStream_t stream)
{
  const float* atom  = (const float*)d_in[0];
  const float* force = (const float*)d_in[1];
  const float* dir   = (const float*)d_in[2];
  const float* dist  = (const float*)d_in[3];
  const int*   eidx  = (const int*)d_in[4];
  const float* Wm1 = (const float*)d_in[5];  const float* bm1 = (const float*)d_in[6];
  const float* Wm2 = (const float*)d_in[7];  const float* bm2 = (const float*)d_in[8];
  const float* Wv1 = (const float*)d_in[9];  const float* bv1 = (const float*)d_in[10];
  const float* Wv2 = (const float*)d_in[11]; const float* bv2 = (const float*)d_in[12];
  const float* Wn1 = (const float*)d_in[13]; const float* bn1 = (const float*)d_in[14];
  const float* Wn2 = (const float*)d_in[15]; const float* bn2 = (const float*)d_in[16];
  const float* Wf1 = (const float*)d_in[17]; const float* bf1 = (const float*)d_in[18];
  const float* Wf2 = (const float*)d_in[19]; const float* bf2 = (const float*)d_in[20];

  const int N = in_sizes[0] / HH;
  const int E = in_sizes[2] / 3;
  const int* rowi = eidx;
  const int* coli = eidx + E;

  // workspace: CSR (~5.3 MB) + bf16 atom/force/dist (~61.5 MB) + bf16 wT (~0.25 MB)
  char* ws = (char*)d_ws;
  size_t off = 0;
  auto take = [&](size_t bytes) -> void* {
    void* p = (void*)(ws + off);
    off += (bytes + 255) & ~(size_t)255;
    return p;
  };
  int* deg      = (int*)take((size_t)(N+1)*4);
  int* rowstart = (int*)take((size_t)(N+1)*4);
  int* cursor   = (int*)take((size_t)N*4);
  int* csr      = (int*)take((size_t)E*4);
  int* destp    = (int*)take((size_t)E*4);
  unsigned short* atom_bf  = (unsigned short*)take((size_t)N*HH*2);
  unsigned short* force_bf = (unsigned short*)take((size_t)N*3*HH*2);
  unsigned short* dist_bf  = (unsigned short*)take((size_t)E*32*2);
  unsigned short* nT1 = (unsigned short*)take(256*128*2);
  unsigned short* nT2 = (unsigned short*)take(128*128*2);
  unsigned short* fT1 = (unsigned short*)take(256*128*2);
  unsigned short* fT2 = (unsigned short*)take(128*128*2);
  if (off > ws_size) return;  // degrade to wrong answer, not a page fault
  (void)n_in; (void)out_size;

  float* out0 = (float*)d_out;                    // scalar_agg -> atom_node_new
  float* out1 = out0 + (size_t)N*HH;              // vec_agg   -> force_node_new

  zero_kernel<<<(N+256)/256, 256, 0, stream>>>(deg, N+1);

  const int na4 = N*HH/4, nf4 = N*3*HH/4, nd4 = E*32/4;
  const int ntot = E + na4 + nf4 + nd4 + 2*256*128 + 2*128*128;
  hist_conv_kernel<<<(ntot+255)/256, 256, 0, stream>>>(rowi, deg, E,
      atom, atom_bf, na4, force, force_bf, nf4, dist, dist_bf, nd4,
      Wn1, nT1, Wn2, nT2, Wf1, fT1, Wf2, fT2);

  scan_kernel<<<1, 1024, 0, stream>>>(deg, rowstart, cursor, N);
  scatter_kernel<<<(E+255)/256, 256, 0, stream>>>(rowi, cursor, csr, destp, E);

  const int nchunks = (N + 15) >> 4;
  int fgrid = nchunks < 256 ? nchunks : 256;
  fused_edge_kernel<<<fgrid, 768, 0, stream>>>(atom_bf, force_bf, dir, dist_bf, coli,
      rowstart, csr, destp,
      Wm1,bm1, Wm2,bm2, Wv1,bv1, Wv2,bv2,
      out0, out1, N, nchunks);

  int gA = (N + 15) >> 4;   if (gA > 512) gA = 512;
  int gB = (3*N + 15) >> 4; if (gB > 512) gB = 512;
  node_both_kernel<<<gA + gB, 512, 0, stream>>>(atom_bf, atom, force_bf,
      out0, out1, force,
      nT1, bn1, nT2, bn2, fT1, bf1, fT2, bf2, N, gA, gB);
}